// Round 17
// baseline (189.356 us; speedup 1.0000x reference)
//
#include <hip/hip_runtime.h>

#define SS 4096
#define DD 1024
#define EE 128
#define SCALE 0.08838834764831845f   // 1/sqrt(128)

typedef __bf16 bf16x8 __attribute__((ext_vector_type(8)));
typedef __bf16 bf16x4 __attribute__((ext_vector_type(4)));
typedef float  f32x4  __attribute__((ext_vector_type(4)));

__device__ __forceinline__ void gload16(const void* g, void* l) {
  __builtin_amdgcn_global_load_lds(
      (const __attribute__((address_space(1))) void*)g,
      (__attribute__((address_space(3))) void*)l, 16, 0, 0);
}

// Grid barrier v3.  R16 bug: RELAXED plain loads can be served by the local
// (non-coherent) XCD L2 -> spin on stale line until eviction (~40us/barrier).
// Fix: poll with atomic RMW fetch_add(0) — RMWs execute at the coherent point
// (IF), never stale, no cache-invalidate side effects.  Leader/flag cascade
// keeps RMW contention low.  One ACQUIRE RMW at exit = single buffer_inv.
__device__ __forceinline__ void gbarrier(unsigned* arr, unsigned* flag,
                                         unsigned target, unsigned phase) {
  __syncthreads();                 // vmcnt(0): this block's writes are in L2
  if (threadIdx.x == 0) {
    __hip_atomic_fetch_add(&arr[(blockIdx.x & 15) * 16], 1u,
                           __ATOMIC_RELEASE, __HIP_MEMORY_SCOPE_AGENT);
    if (blockIdx.x == 0) {
      unsigned s;
      do {
        __builtin_amdgcn_s_sleep(2);
        unsigned v[16];
        #pragma unroll
        for (int i = 0; i < 16; ++i)     // 16 RMWs issue back-to-back,
          v[i] = __hip_atomic_fetch_add(&arr[i * 16], 0u,   // in flight
                     __ATOMIC_RELAXED, __HIP_MEMORY_SCOPE_AGENT);
        s = 0;
        #pragma unroll
        for (int i = 0; i < 16; ++i) s += v[i];
      } while (s < target);
      #pragma unroll
      for (int i = 0; i < 8; ++i)
        __hip_atomic_fetch_add(&flag[i * 16], 1u,
                               __ATOMIC_RELEASE, __HIP_MEMORY_SCOPE_AGENT);
    } else {
      unsigned* f = &flag[(blockIdx.x & 7) * 16];
      while (__hip_atomic_fetch_add(f, 0u, __ATOMIC_RELAXED,
                                    __HIP_MEMORY_SCOPE_AGENT) < phase)
        __builtin_amdgcn_s_sleep(8);
    }
    (void)__hip_atomic_fetch_add(&flag[(blockIdx.x & 7) * 16], 0u,
                                 __ATOMIC_ACQUIRE, __HIP_MEMORY_SCOPE_AGENT);
  }
  __syncthreads();
}

// ---------------------------------------------------------------------------
// Mega-kernel: P0 wcast -> P1 proj (R10 body) -> P2 ktv -> P3 reduce -> P4 qm
// grid 768 x 128 thr, 32 KB LDS (5 blocks/CU capacity >= 3 needed).
// ---------------------------------------------------------------------------
__global__ __launch_bounds__(128, 2) void mega_kernel(
    const float* __restrict__ x,
    const float* __restrict__ qW, const float* __restrict__ qB,
    const float* __restrict__ kW, const float* __restrict__ kB,
    const float* __restrict__ vW, const float* __restrict__ vB,
    float* __restrict__ out, char* __restrict__ ws)
{
  __bf16* Wb  = (__bf16*)ws;                       // 768 KB
  __bf16* Qbf = (__bf16*)(ws + (1u  << 20));       // 2 MB (scaled Q)
  __bf16* KT  = (__bf16*)(ws + (3u  << 20));       // 2 MB
  __bf16* VT  = (__bf16*)(ws + (5u  << 20));       // 2 MB
  float*  part= (float*) (ws + (7u  << 20));       // 8 MB
  __bf16* MT  = (__bf16*)(ws + (15u << 20));       // 64 KB
  unsigned* arr  = (unsigned*)(ws + (15u << 20) + (128u << 10));
  unsigned* flag = arr + 256;                      // 16*64B after arr

  __shared__ __attribute__((aligned(16))) __bf16 ldsA[2][64 * 64];  // 16 KB
  __shared__ __attribute__((aligned(16))) __bf16 ldsB[2][64 * 64];  // 16 KB

  const int tid  = threadIdx.x;
  const int id   = blockIdx.x;
  const int w    = tid >> 6, lane = tid & 63;
  const int l15  = lane & 15, l4 = lane >> 4;

  // ================= P0: cast W (q|k|v) -> bf16 Wb =================
  {
    const int gtid = id * 128 + tid;               // 98304 threads
    if (gtid < 49152) {                            // 49152 bf16x8 chunks
      const int m = gtid >> 14;                    // 16384 chunks/matrix
      const size_t o = (size_t)(gtid & 16383) * 8;
      const float* src = (m == 0) ? qW : (m == 1 ? kW : vW);
      float4 u0 = *(const float4*)&src[o];
      float4 u1 = *(const float4*)&src[o + 4];
      bf16x8 v = { (__bf16)u0.x, (__bf16)u0.y, (__bf16)u0.z, (__bf16)u0.w,
                   (__bf16)u1.x, (__bf16)u1.y, (__bf16)u1.z, (__bf16)u1.w };
      *(bf16x8*)&Wb[(size_t)m * 131072 + o] = v;
    }
  }
  gbarrier(arr, flag, 768, 1);

  // ================= P1: fused QKV projection (R10 body) =================
  {
    const int swz  = (id & 7) * 96 + (id >> 3);    // XCD-chunked bijective
    const int rt   = swz / 6, ct = swz % 6;
    const int row0 = rt * 64;                      // flat row [0,8192)
    const int g0   = ct * 64;                      // col base [0,384)

    const int arow0 = w * 4 + (lane >> 4);
    const int acolv = lane & 15;
    const float* gA = x + (size_t)(row0 + arow0) * DD + acolv * 4;
    const int acc16 = acolv >> 1, ahalf = acolv & 1;

    const int bRow = lane >> 3;
    const int cB   = (lane & 7) ^ bRow;
    const __bf16* gB = Wb + (size_t)(g0 + w * 32 + bRow) * DD + cB * 8;

    f32x4 acc[4][2] = {};
    f32x4 rA0[8], rA1[8];

#define AISSUE(RS, T) {                                                      \
    const float* g_ = gA + (T) * 64;                                         \
    _Pragma("unroll") for (int j = 0; j < 8; ++j)                            \
      RS[j] = *(const f32x4*)(g_ + (size_t)j * 8 * DD);                      }

#define AWRITE(P, RS) {                                                      \
    _Pragma("unroll") for (int j = 0; j < 8; ++j) {                          \
      bf16x4 v_ = { (__bf16)RS[j][0], (__bf16)RS[j][1],                      \
                    (__bf16)RS[j][2], (__bf16)RS[j][3] };                    \
      const int r_ = arow0 + j * 8;                                          \
      *(bf16x4*)&ldsA[P][r_ * 64 + (((acc16 ^ (r_ & 7)) << 3) + ahalf * 4)]  \
          = v_;                                                              \
    } }

#define BSTAGE(P, T) {                                                       \
    _Pragma("unroll") for (int j = 0; j < 4; ++j)                            \
      gload16(gB + (T) * 64 + (size_t)j * 8 * DD,                            \
              &ldsB[P][(w * 32 + j * 8) * 64]);                              }

#define COMPUTE(P) {                                                         \
    const int rs7 = l15 & 7;                                                 \
    _Pragma("unroll") for (int ks = 0; ks < 2; ++ks) {                       \
      const int so = ((ks * 4 + l4) ^ rs7) << 3;                             \
      bf16x8 af[4], bq[2];                                                   \
      _Pragma("unroll") for (int m = 0; m < 4; ++m)                          \
        af[m] = *(const bf16x8*)&ldsA[P][(m * 16 + l15) * 64 + so];          \
      _Pragma("unroll") for (int n = 0; n < 2; ++n)                          \
        bq[n] = *(const bf16x8*)&ldsB[P][(w * 32 + n * 16 + l15) * 64 + so]; \
      _Pragma("unroll") for (int m = 0; m < 4; ++m)                          \
        _Pragma("unroll") for (int n = 0; n < 2; ++n)                        \
          acc[m][n] = __builtin_amdgcn_mfma_f32_16x16x32_bf16(               \
              af[m], bq[n], acc[m][n], 0, 0, 0);                             \
    } }

#define HEADBAR(VN) {                                                        \
    asm volatile("s_waitcnt vmcnt(" #VN ") lgkmcnt(0)" ::: "memory");        \
    __builtin_amdgcn_s_barrier();                                            \
    asm volatile("" ::: "memory"); }

    AISSUE(rA0, 0);
    BSTAGE(0, 0);
    __builtin_amdgcn_sched_barrier(0);
    AISSUE(rA1, 1);
    __builtin_amdgcn_sched_barrier(0);
    AWRITE(0, rA0);

    for (int t = 0; t < 14; t += 2) {
      HEADBAR(8);
      COMPUTE(0);
      BSTAGE(1, t + 1);
      __builtin_amdgcn_sched_barrier(0);
      AISSUE(rA0, t + 2);
      __builtin_amdgcn_sched_barrier(0);
      AWRITE(1, rA1);
      HEADBAR(8);
      COMPUTE(1);
      BSTAGE(0, t + 2);
      __builtin_amdgcn_sched_barrier(0);
      AISSUE(rA1, t + 3);
      __builtin_amdgcn_sched_barrier(0);
      AWRITE(0, rA0);
    }
    HEADBAR(8);
    COMPUTE(0);
    BSTAGE(1, 15);
    __builtin_amdgcn_sched_barrier(0);
    AWRITE(1, rA1);
    HEADBAR(0);
    COMPUTE(1);
#undef AISSUE
#undef AWRITE
#undef BSTAGE
#undef COMPUTE
#undef HEADBAR
    __syncthreads();

    const float* bias = (g0 < 128) ? qB : (g0 < 256 ? kB : vB);
    const int bofs = (g0 < 128) ? g0 : (g0 < 256 ? g0 - 128 : g0 - 256);

    if (ct < 2) {                                  // Q: row-major, *SCALE
      #pragma unroll
      for (int m = 0; m < 4; ++m)
        #pragma unroll
        for (int n = 0; n < 2; ++n) {
          const int col = w * 32 + n * 16 + l15;
          const float bv = bias[bofs + col];
          #pragma unroll
          for (int r = 0; r < 4; ++r) {
            const int row = row0 + m * 16 + l4 * 4 + r;
            Qbf[(size_t)row * EE + g0 + col] =
                (__bf16)((acc[m][n][r] + bv) * SCALE);
          }
        }
    } else {                                       // K/V: transpose via LDS
      __bf16* Tb = (__bf16*)ldsA;                  // [64 cols][64 rows chunkXOR]
      #pragma unroll
      for (int m = 0; m < 4; ++m)
        #pragma unroll
        for (int n = 0; n < 2; ++n) {
          const int tc = w * 32 + n * 16 + l15;
          const float bv = bias[bofs + tc];
          #pragma unroll
          for (int r = 0; r < 4; ++r) {
            const int rl = m * 16 + l4 * 4 + r;
            Tb[tc * 64 + (((rl >> 3) ^ (tc & 7)) << 3) + (rl & 7)] =
                (__bf16)(acc[m][n][r] + bv);
          }
        }
      __syncthreads();
      const int col = tid >> 1, p2 = tid & 1;      // 64 cols x 2 thr
      const int b = row0 >> 12, s0 = row0 & 4095;
      __bf16* dst = (ct < 4)
          ? &KT[((size_t)b * EE + (ct - 2) * 64 + col) * SS + s0]
          : &VT[((size_t)b * EE + (ct - 4) * 64 + col) * SS + s0];
      #pragma unroll
      for (int j = 0; j < 4; ++j) {
        const int ch = p2 * 4 + j;                 // 8 chunks of 8 bf16
        bf16x8 v = *(const bf16x8*)&Tb[col * 64 + ((ch ^ (col & 7)) << 3)];
        *(bf16x8*)&dst[ch * 8] = v;
      }
    }
  }
  gbarrier(arr, flag, 1536, 2);

  // ================= P2: partial K^T V (512 active blocks) =================
  if (id < 512) {
    const int c = id & 63, q = id >> 6;
    const int fq = q & 3, b = q >> 2;
    const int s0 = c * 64;
    const int fbase = fq * 32 + w * 16;            // w in {0,1}
    const __bf16* Kb = KT + (size_t)b * EE * SS;
    const __bf16* Vb = VT + (size_t)b * EE * SS;

    f32x4 acc2[8] = {};
    #pragma unroll
    for (int ks = 0; ks < 2; ++ks) {
      const int s = s0 + ks * 32 + 8 * l4;
      bf16x8 bv = *(const bf16x8*)&Vb[(size_t)(fbase + l15) * SS + s];
      #pragma unroll
      for (int i = 0; i < 8; ++i) {
        bf16x8 av = *(const bf16x8*)&Kb[(size_t)(i * 16 + l15) * SS + s];
        acc2[i] = __builtin_amdgcn_mfma_f32_16x16x32_bf16(av, bv, acc2[i], 0, 0, 0);
      }
    }
    float* P = part + (size_t)(b * 64 + c) * 16384;
    #pragma unroll
    for (int i = 0; i < 8; ++i)
      #pragma unroll
      for (int r = 0; r < 4; ++r)
        P[(i * 16 + l4 * 4 + r) * 128 + fbase + l15] = acc2[i][r];
  }
  gbarrier(arr, flag, 2304, 3);

  // ================= P3: reduce 64 partials -> MT[b][f][e] =================
  if (id < 256) {
    const int b = id >> 7;
    const int e = id & 127;
    const int f = tid;                             // 0..127
    float s = 0.f;
    for (int cc = 0; cc < 64; ++cc)
      s += part[(size_t)(b * 64 + cc) * 16384 + e * 128 + f];
    MT[((size_t)b * EE + f) * EE + e] = (__bf16)s;
  }
  gbarrier(arr, flag, 3072, 4);

  // ================= P4: O = Q * M (256 active blocks) =================
  if (id < 256) {
    const int b = id >> 7, bx = id & 127;
    const int row0q = bx * 32 + w * 16;
    const __bf16* Qb = Qbf + (size_t)b * SS * EE;
    const __bf16* Mb = MT + (size_t)b * EE * EE;

    f32x4 acc3[8] = {};
    #pragma unroll
    for (int ks = 0; ks < 4; ++ks) {
      const int e = ks * 32 + 8 * l4;
      bf16x8 av = *(const bf16x8*)&Qb[(size_t)(row0q + l15) * EE + e];
      #pragma unroll
      for (int j = 0; j < 8; ++j) {
        bf16x8 bv = *(const bf16x8*)&Mb[(size_t)(j * 16 + l15) * EE + e];
        acc3[j] = __builtin_amdgcn_mfma_f32_16x16x32_bf16(av, bv, acc3[j], 0, 0, 0);
      }
    }
    #pragma unroll
    for (int j = 0; j < 8; ++j)
      #pragma unroll
      for (int r = 0; r < 4; ++r)
        out[((size_t)b * SS + row0q + l4 * 4 + r) * EE + j * 16 + l15] =
            acc3[j][r];
  }
}

extern "C" void kernel_launch(void* const* d_in, const int* in_sizes, int n_in,
                              void* d_out, int out_size, void* d_ws, size_t ws_size,
                              hipStream_t stream) {
  const float* x  = (const float*)d_in[0];
  const float* qW = (const float*)d_in[1];
  const float* qB = (const float*)d_in[2];
  const float* kW = (const float*)d_in[3];
  const float* kB = (const float*)d_in[4];
  const float* vW = (const float*)d_in[5];
  const float* vB = (const float*)d_in[6];
  float* out = (float*)d_out;
  char* ws = (char*)d_ws;

  // zero arrival counters (16x64B) + flags (8x64B)
  hipMemsetAsync(ws + (15u << 20) + (128u << 10), 0, 2048, stream);
  mega_kernel<<<dim3(768), 128, 0, stream>>>(x, qW, qB, kW, kB, vW, vB, out, ws);
}

// Round 18
// 41.201 us; speedup vs baseline: 4.5959x; 4.5959x over previous
//
#include <hip/hip_runtime.h>

#define SS 4096
#define DD 1024
#define EE 128
#define SCALE 0.08838834764831845f   // 1/sqrt(128)

typedef __bf16 bf16x8 __attribute__((ext_vector_type(8)));
typedef __bf16 bf16x4 __attribute__((ext_vector_type(4)));
typedef float  f32x4  __attribute__((ext_vector_type(4)));

__device__ __forceinline__ void gload16(const void* g, void* l) {
  __builtin_amdgcn_global_load_lds(
      (const __attribute__((address_space(1))) void*)g,
      (__attribute__((address_space(3))) void*)l, 16, 0, 0);
}

// ---------------------------------------------------------------------------
// K0: cast W (q|k|v, each 128x1024 fp32) to bf16 Wb[384][1024].
// ---------------------------------------------------------------------------
__global__ __launch_bounds__(256) void wcast_kernel(
    const float* __restrict__ qW, const float* __restrict__ kW,
    const float* __restrict__ vW, __bf16* __restrict__ Wb)
{
  const int m = blockIdx.y;
  const float* src = (m == 0) ? qW : (m == 1 ? kW : vW);
  const size_t o = ((size_t)blockIdx.x * 256 + threadIdx.x) * 8;
  float4 u0 = *(const float4*)&src[o];
  float4 u1 = *(const float4*)&src[o + 4];
  bf16x8 v = { (__bf16)u0.x, (__bf16)u0.y, (__bf16)u0.z, (__bf16)u0.w,
               (__bf16)u1.x, (__bf16)u1.y, (__bf16)u1.z, (__bf16)u1.w };
  *(bf16x8*)&Wb[(size_t)m * EE * DD + o] = v;
}

// ---------------------------------------------------------------------------
// K1: fused QKV projection.  BM=64 BN=64 BK=64; grid 768 (3 blocks/CU),
// 128 thr (2 waves, wave-tile 64 rows x 32 cols: 12 LDS reads / 16 MFMA).
// A: reg-staged fp32 (4KB-contiguous wave loads) -> bf16 -> swizzled ds_write,
//    2-tile reg prefetch.  B: source-swizzled global_load_lds, 1-tile dbuf.
// Counted vmcnt + raw s_barrier (loads in flight across barriers).
// Q epilogue folds *SCALE into Qbf.
// ---------------------------------------------------------------------------
__global__ __launch_bounds__(128, 2) void proj_kernel(
    const float* __restrict__ x, const __bf16* __restrict__ Wb,
    const float* __restrict__ qB, const float* __restrict__ kB,
    const float* __restrict__ vB,
    __bf16* __restrict__ Qbf, __bf16* __restrict__ KT, __bf16* __restrict__ VT)
{
  __shared__ __attribute__((aligned(16))) __bf16 ldsA[2][64 * 64];  // 16 KB
  __shared__ __attribute__((aligned(16))) __bf16 ldsB[2][64 * 64];  // 16 KB

  const int tid  = threadIdx.x;
  const int w    = tid >> 6, lane = tid & 63;
  const int l15  = lane & 15, l4 = lane >> 4;

  // XCD-chunked bijective swizzle (768 % 8 == 0), rtile-major within XCD
  const int id   = blockIdx.x;
  const int swz  = (id & 7) * 96 + (id >> 3);
  const int rt   = swz / 6, ct = swz % 6;
  const int row0 = rt * 64;                     // flat row [0,8192)
  const int g0   = ct * 64;                     // col base [0,384)

  // ---- A reg-staging: instr j covers rows j*8+w*4+(lane>>4), 4KB contiguous
  const int arow0 = w * 4 + (lane >> 4);        // row base for j=0 (step 8)
  const int acolv = lane & 15;                  // f32x4 index within row
  const float* gA = x + (size_t)(row0 + arow0) * DD + acolv * 4;
  // write-side: chunk cc = acolv>>1 (16B), half = acolv&1 (8B within chunk)
  const int acc16 = acolv >> 1, ahalf = acolv & 1;

  // ---- B staging: dest row r = w*32 + j*8 + (lane>>3); r&7 = lane>>3
  const int bRow = lane >> 3;
  const int cB   = (lane & 7) ^ bRow;
  const __bf16* gB = Wb + (size_t)(g0 + w * 32 + bRow) * DD + cB * 8;

  f32x4 acc[4][2] = {};
  f32x4 rA0[8], rA1[8];

#define AISSUE(RS, T) {                                                      \
    const float* g_ = gA + (T) * 64;                                         \
    _Pragma("unroll") for (int j = 0; j < 8; ++j)                            \
      RS[j] = *(const f32x4*)(g_ + (size_t)j * 8 * DD);                      }

#define AWRITE(P, RS) {                                                      \
    _Pragma("unroll") for (int j = 0; j < 8; ++j) {                          \
      bf16x4 v_ = { (__bf16)RS[j][0], (__bf16)RS[j][1],                      \
                    (__bf16)RS[j][2], (__bf16)RS[j][3] };                    \
      const int r_ = arow0 + j * 8;                                          \
      *(bf16x4*)&ldsA[P][r_ * 64 + (((acc16 ^ (r_ & 7)) << 3) + ahalf * 4)]  \
          = v_;                                                              \
    } }

#define BSTAGE(P, T) {                                                       \
    _Pragma("unroll") for (int j = 0; j < 4; ++j)                            \
      gload16(gB + (T) * 64 + (size_t)j * 8 * DD,                            \
              &ldsB[P][(w * 32 + j * 8) * 64]);                              }

#define COMPUTE(P) {                                                         \
    const int rs7 = l15 & 7;                                                 \
    _Pragma("unroll") for (int ks = 0; ks < 2; ++ks) {                       \
      const int so = ((ks * 4 + l4) ^ rs7) << 3;                             \
      bf16x8 af[4], bq[2];                                                   \
      _Pragma("unroll") for (int m = 0; m < 4; ++m)                          \
        af[m] = *(const bf16x8*)&ldsA[P][(m * 16 + l15) * 64 + so];          \
      _Pragma("unroll") for (int n = 0; n < 2; ++n)                          \
        bq[n] = *(const bf16x8*)&ldsB[P][(w * 32 + n * 16 + l15) * 64 + so]; \
      _Pragma("unroll") for (int m = 0; m < 4; ++m)                          \
        _Pragma("unroll") for (int n = 0; n < 2; ++n)                        \
          acc[m][n] = __builtin_amdgcn_mfma_f32_16x16x32_bf16(               \
              af[m], bq[n], acc[m][n], 0, 0, 0);                             \
    } }

#define HEADBAR(VN) {                                                        \
    asm volatile("s_waitcnt vmcnt(" #VN ") lgkmcnt(0)" ::: "memory");        \
    __builtin_amdgcn_s_barrier();                                            \
    asm volatile("" ::: "memory"); }

  // ---- prologue ----
  AISSUE(rA0, 0);
  BSTAGE(0, 0);
  __builtin_amdgcn_sched_barrier(0);
  AISSUE(rA1, 1);
  __builtin_amdgcn_sched_barrier(0);
  AWRITE(0, rA0);                        // auto-wait drains A(0)

  // steady head invariant: outstanding = B(t)*4 + A(t+1)*8 = 12
  for (int t = 0; t < 14; t += 2) {
    HEADBAR(8);                          // drain B(t), keep A(t+1)
    COMPUTE(0);
    BSTAGE(1, t + 1);
    __builtin_amdgcn_sched_barrier(0);
    AISSUE(rA0, t + 2);
    __builtin_amdgcn_sched_barrier(0);
    AWRITE(1, rA1);                      // auto vmcnt(12): A(t+1) landed
    HEADBAR(8);
    COMPUTE(1);
    BSTAGE(0, t + 2);
    __builtin_amdgcn_sched_barrier(0);
    AISSUE(rA1, t + 3);
    __builtin_amdgcn_sched_barrier(0);
    AWRITE(0, rA0);                      // A(t+2)
  }
  HEADBAR(8);                            // t=14
  COMPUTE(0);
  BSTAGE(1, 15);
  __builtin_amdgcn_sched_barrier(0);
  AWRITE(1, rA1);                        // A(15); auto vmcnt(4)
  HEADBAR(0);                            // t=15: drain B(15)
  COMPUTE(1);
#undef AISSUE
#undef AWRITE
#undef BSTAGE
#undef COMPUTE
#undef HEADBAR
  __syncthreads();

  const float* bias = (g0 < 128) ? qB : (g0 < 256 ? kB : vB);
  const int bofs = (g0 < 128) ? g0 : (g0 < 256 ? g0 - 128 : g0 - 256);

  if (ct < 2) {                                  // Q: row-major, *SCALE folded
    #pragma unroll
    for (int m = 0; m < 4; ++m)
      #pragma unroll
      for (int n = 0; n < 2; ++n) {
        const int col = w * 32 + n * 16 + l15;
        const float bv = bias[bofs + col];
        #pragma unroll
        for (int r = 0; r < 4; ++r) {
          const int row = row0 + m * 16 + l4 * 4 + r;
          Qbf[(size_t)row * EE + g0 + col] =
              (__bf16)((acc[m][n][r] + bv) * SCALE);
        }
      }
  } else {                                       // K/V: transpose via LDS
    __bf16* Tb = (__bf16*)ldsA;                  // [64 cols][64 rows chunkXOR]
    #pragma unroll
    for (int m = 0; m < 4; ++m)
      #pragma unroll
      for (int n = 0; n < 2; ++n) {
        const int tc = w * 32 + n * 16 + l15;
        const float bv = bias[bofs + tc];
        #pragma unroll
        for (int r = 0; r < 4; ++r) {
          const int rl = m * 16 + l4 * 4 + r;
          Tb[tc * 64 + (((rl >> 3) ^ (tc & 7)) << 3) + (rl & 7)] =
              (__bf16)(acc[m][n][r] + bv);
        }
      }
    __syncthreads();
    const int col = tid >> 1, p2 = tid & 1;      // 64 cols x 2 thr
    const int b = row0 >> 12, s0 = row0 & 4095;
    __bf16* dst = (ct < 4)
        ? &KT[((size_t)b * EE + (ct - 2) * 64 + col) * SS + s0]
        : &VT[((size_t)b * EE + (ct - 4) * 64 + col) * SS + s0];
    #pragma unroll
    for (int j = 0; j < 4; ++j) {
      const int ch = p2 * 4 + j;                 // 8 chunks of 8 bf16
      bf16x8 v = *(const bf16x8*)&Tb[col * 64 + ((ch ^ (col & 7)) << 3)];
      *(bf16x8*)&dst[ch * 8] = v;
    }
  }
}

// ---------------------------------------------------------------------------
// K2: partial K^T V.  grid (64 s-chunks, 2 f-halves, 2 b) x 256 thr.
// ---------------------------------------------------------------------------
__global__ __launch_bounds__(256) void ktv_kernel(
    const __bf16* __restrict__ KT, const __bf16* __restrict__ VT,
    float* __restrict__ part)
{
  const int c = blockIdx.x, fh = blockIdx.y, b = blockIdx.z;
  const int tid = threadIdx.x;
  const int w = tid >> 6, lane = tid & 63;
  const int l15 = lane & 15, l4 = lane >> 4;
  const int s0 = c * 64;
  const int fbase = fh * 64 + w * 16;
  const __bf16* Kb = KT + (size_t)b * EE * SS;
  const __bf16* Vb = VT + (size_t)b * EE * SS;

  f32x4 acc[8] = {};
  #pragma unroll
  for (int ks = 0; ks < 2; ++ks) {
    const int s = s0 + ks * 32 + 8 * l4;
    bf16x8 bv = *(const bf16x8*)&Vb[(size_t)(fbase + l15) * SS + s];
    #pragma unroll
    for (int i = 0; i < 8; ++i) {
      bf16x8 av = *(const bf16x8*)&Kb[(size_t)(i * 16 + l15) * SS + s];
      acc[i] = __builtin_amdgcn_mfma_f32_16x16x32_bf16(av, bv, acc[i], 0, 0, 0);
    }
  }
  float* P = part + (size_t)(b * 64 + c) * 16384;
  #pragma unroll
  for (int i = 0; i < 8; ++i)
    #pragma unroll
    for (int r = 0; r < 4; ++r) {
      int e = i * 16 + l4 * 4 + r;
      int f = fbase + l15;
      P[e * 128 + f] = acc[i][r];
    }
}

// ---------------------------------------------------------------------------
// K3: reduce 64 partials -> MT[b][f][e] = sum (scale folded into Qbf).
// ---------------------------------------------------------------------------
__global__ __launch_bounds__(256) void reduce_kernel(
    const float* __restrict__ part, __bf16* __restrict__ MT)
{
  const int b = blockIdx.y;
  const int e = blockIdx.x * 2 + (threadIdx.x >> 7);
  const int f = threadIdx.x & 127;
  float s = 0.f;
  for (int cc = 0; cc < 64; ++cc)
    s += part[(size_t)(b * 64 + cc) * 16384 + e * 128 + f];
  MT[((size_t)b * EE + f) * EE + e] = (__bf16)s;
}

// ---------------------------------------------------------------------------
// K4: O = Q * M  (MT[f][e]).  grid (128, 2) x 128 thr.
// ---------------------------------------------------------------------------
__global__ __launch_bounds__(128) void qm_kernel(
    const __bf16* __restrict__ Qbf, const __bf16* __restrict__ MT,
    float* __restrict__ out)
{
  const int b = blockIdx.y;
  const int tid = threadIdx.x;
  const int w = tid >> 6, lane = tid & 63;
  const int l15 = lane & 15, l4 = lane >> 4;
  const int row0 = blockIdx.x * 32 + w * 16;
  const __bf16* Qb = Qbf + (size_t)b * SS * EE;
  const __bf16* Mb = MT + (size_t)b * EE * EE;

  f32x4 acc[8] = {};
  #pragma unroll
  for (int ks = 0; ks < 4; ++ks) {
    const int e = ks * 32 + 8 * l4;
    bf16x8 av = *(const bf16x8*)&Qb[(size_t)(row0 + l15) * EE + e];
    #pragma unroll
    for (int j = 0; j < 8; ++j) {
      bf16x8 bv = *(const bf16x8*)&Mb[(size_t)(j * 16 + l15) * EE + e];
      acc[j] = __builtin_amdgcn_mfma_f32_16x16x32_bf16(av, bv, acc[j], 0, 0, 0);
    }
  }
  #pragma unroll
  for (int j = 0; j < 8; ++j)
    #pragma unroll
    for (int r = 0; r < 4; ++r) {
      int srow = row0 + l4 * 4 + r;
      int f = j * 16 + l15;
      out[((size_t)b * SS + srow) * EE + f] = acc[j][r];
    }
}

extern "C" void kernel_launch(void* const* d_in, const int* in_sizes, int n_in,
                              void* d_out, int out_size, void* d_ws, size_t ws_size,
                              hipStream_t stream) {
  const float* x  = (const float*)d_in[0];
  const float* qW = (const float*)d_in[1];
  const float* qB = (const float*)d_in[2];
  const float* kW = (const float*)d_in[3];
  const float* kB = (const float*)d_in[4];
  const float* vW = (const float*)d_in[5];
  const float* vB = (const float*)d_in[6];
  float* out = (float*)d_out;

  char* base = (char*)d_ws;
  __bf16* Wb  = (__bf16*)(base);                         // 768 KB
  __bf16* Qbf = (__bf16*)(base + (1u  << 20));           // 2 MB
  __bf16* KT  = (__bf16*)(base + (3u  << 20));           // 2 MB
  __bf16* VT  = (__bf16*)(base + (5u  << 20));           // 2 MB
  float*  part= (float*) (base + (7u  << 20));           // 8 MB
  __bf16* MT  = (__bf16*)(base + (15u << 20));           // 64 KB

  wcast_kernel <<<dim3(64, 3),    256, 0, stream>>>(qW, kW, vW, Wb);
  proj_kernel  <<<dim3(768),      128, 0, stream>>>(x, Wb, qB, kB, vB, Qbf, KT, VT);
  ktv_kernel   <<<dim3(64, 2, 2), 256, 0, stream>>>(KT, VT, part);
  reduce_kernel<<<dim3(64, 2),    256, 0, stream>>>(part, MT);
  qm_kernel    <<<dim3(128, 2),   128, 0, stream>>>(Qbf, MT, out);
}